// Round 5
// baseline (380.767 us; speedup 1.0000x reference)
//
#include <hip/hip_runtime.h>

// ConvRecLayer: dynamic conv (H=16, K=15, causal) + LayerNorm + FFN(relu) + residual
// T=1024 B=8 C=1024 F=4096. Inputs/outputs fp32 (per reference); internal compute bf16 MFMA.

#define T_DIM 1024
#define B_DIM 8
#define C_DIM 1024
#define F_DIM 4096
#define H_DIM 16
#define K_TAP 15
#define TB (T_DIM * B_DIM)   // 8192 rows

typedef __attribute__((ext_vector_type(8))) short short8;
typedef __attribute__((ext_vector_type(4))) float f32x4;

__device__ __forceinline__ float bf2f(unsigned short u) {
    union { unsigned int i; float f; } v; v.i = ((unsigned int)u) << 16; return v.f;
}
__device__ __forceinline__ unsigned short f2bf(float f) {
    union { float f; unsigned int i; } v; v.f = f;
    unsigned int r = v.i + 0x7fffu + ((v.i >> 16) & 1u);  // RNE
    return (unsigned short)(r >> 16);
}

// async global->LDS DMA, 16B per lane: lane i reads gptr(lane) -> ldsbase + i*16
__device__ __forceinline__ void async_copy16(const void* gptr, void* lptr) {
    __builtin_amdgcn_global_load_lds(
        (const __attribute__((address_space(1))) void*)gptr,
        (__attribute__((address_space(3))) void*)lptr, 16, 0, 0);
}

// ---------------------------------------------------------------------------
// cvt_bf16: fp32 -> bf16, 4 elems/thread. n must be multiple of 1024.
// ---------------------------------------------------------------------------
__global__ void cvt_bf16(const float* __restrict__ in, unsigned short* __restrict__ out) {
    int i = (blockIdx.x * 256 + threadIdx.x) * 4;
    float4 v = *(const float4*)(in + i);
    unsigned short a = f2bf(v.x), b = f2bf(v.y), c = f2bf(v.z), d = f2bf(v.w);
    uint2 o;
    o.x = (unsigned int)a | ((unsigned int)b << 16);
    o.y = (unsigned int)c | ((unsigned int)d << 16);
    *(uint2*)(out + i) = o;
}

// ---------------------------------------------------------------------------
// transpose_pad: in is R x Cin (fp32, row-major). out is Cpad x R (bf16), rows
// >= Cin zero-filled. Grid: (Cpad/32, R/32), block (32,8).
// ---------------------------------------------------------------------------
__global__ void transpose_pad(const float* __restrict__ in,
                              unsigned short* __restrict__ out,
                              int R, int Cin, int Cpad) {
    __shared__ unsigned short tile[32][33];
    const int c0 = blockIdx.x * 32, r0 = blockIdx.y * 32;
    const int x = threadIdx.x, y = threadIdx.y;
#pragma unroll
    for (int j = 0; j < 4; j++) {
        int r = r0 + y + j * 8, c = c0 + x;
        unsigned short v = 0;
        if (c < Cin) v = f2bf(in[(size_t)r * Cin + c]);
        tile[y + j * 8][x] = v;
    }
    __syncthreads();
#pragma unroll
    for (int j = 0; j < 4; j++) {
        out[(size_t)(c0 + y + j * 8) * R + (r0 + x)] = tile[x][y + j * 8];
    }
}

// ---------------------------------------------------------------------------
// gemm_bt: C[M x N] = A[M x K] @ Bt[N x K]^T  (bf16 in, fp32 acc)
// 128x128 block tile, 4 waves each computing 64x64 via 4x4 MFMA 16x16x32 tiles.
// Staging via global_load_lds width=16 into a TRIPLE-BUFFERED LDS tile with a
// DEPTH-2 software pipeline: iter k waits `s_waitcnt vmcnt(4)` (drains exactly
// tile k's 4 DMAs, leaves tile k+1's 4 in flight ACROSS the barrier — the
// hipBLASLt/AITER fine-grained-vmcnt technique), raw s_barrier, then issues
// tile k+2 into buf (k+2)%3 and computes tile k. Each tile gets ~2 compute
// phases of DMA-latency cover. __syncthreads() is NOT used in the K-loop (its
// implicit vmcnt(0) would collapse the pipeline to depth 1).
// LDS layout [128 rows][32 k], XOR-swizzled on the GLOBAL address side
// (chunk kc of row r at slot kc ^ ((r>>1)&3)); fragment ds_read_b128s are
// verified conflict-free (SQ_LDS_BANK_CONFLICT = 0).
// MODE 1: bf16 out = relu(acc + bias[n])
// MODE 2: fp32 out = acc + bias[n] + resid[m][n]   (resid bf16)
// MODE 3: fp32 out = acc
// Requires M%128==0, N%128==0, K%32==0, K >= 64.
// ---------------------------------------------------------------------------
template <int MODE>
__global__ __launch_bounds__(256)
void gemm_bt(const unsigned short* __restrict__ A,
             const unsigned short* __restrict__ Bt,
             void* __restrict__ Cout_v,
             int M, int N, int K,
             const float* __restrict__ bias,
             const unsigned short* __restrict__ resid) {
    __shared__ __align__(16) unsigned short As[3][128 * 32];
    __shared__ __align__(16) unsigned short Bs[3][128 * 32];

    const int tid = threadIdx.x;
    const int m0 = blockIdx.y * 128;
    const int n0 = blockIdx.x * 128;
    const int wave = tid >> 6, lane = tid & 63;
    const int quad = lane >> 4, l16 = lane & 15;
    const int wm = (wave >> 1) * 64;  // wave row offset in tile
    const int wn = (wave & 1) * 64;   // wave col offset in tile

    f32x4 acc[4][4];
#pragma unroll
    for (int i = 0; i < 4; i++)
#pragma unroll
        for (int j = 0; j < 4; j++) acc[i][j] = (f32x4){0.f, 0.f, 0.f, 0.f};

    // ---- DMA staging addresses -------------------------------------------
    // wave w stages rows [w*32, w*32+32) of both A and B tiles, as two
    // 16-row issues per operand. Lane i covers (row = i>>2, stored chunk
    // kc_s = i&3); the global chunk it fetches is kc_s ^ ((row>>1)&3).
    const int r_local = lane >> 2;                       // 0..15
    const int kc_g = (lane & 3) ^ ((lane >> 3) & 3);     // swizzled global chunk
    const unsigned short* gA0 = A + (size_t)(m0 + wave * 32 + r_local) * K + kc_g * 8;
    const unsigned short* gA1 = gA0 + (size_t)16 * K;
    const unsigned short* gB0 = Bt + (size_t)(n0 + wave * 32 + r_local) * K + kc_g * 8;
    const unsigned short* gB1 = gB0 + (size_t)16 * K;
    unsigned short* lA[3] = {&As[0][wave * 32 * 32], &As[1][wave * 32 * 32], &As[2][wave * 32 * 32]};
    unsigned short* lB[3] = {&Bs[0][wave * 32 * 32], &Bs[1][wave * 32 * 32], &Bs[2][wave * 32 * 32]};

    const int xorsw = (l16 >> 1) & 3;                    // fragment-read swizzle

    // prologue: stage tiles 0 and 1 (K >= 64 for all call sites)
    async_copy16(gA0, lA[0]);
    async_copy16(gA1, lA[0] + 16 * 32);
    async_copy16(gB0, lB[0]);
    async_copy16(gB1, lB[0] + 16 * 32);
    async_copy16(gA0 + 32, lA[1]);
    async_copy16(gA1 + 32, lA[1] + 16 * 32);
    async_copy16(gB0 + 32, lB[1]);
    async_copy16(gB1 + 32, lB[1] + 16 * 32);

    int cur = 0;
    for (int k0 = 0; k0 < K; k0 += 32) {
        // drain exactly tile k's 4 DMAs; keep tile k+1's in flight
        if (k0 + 32 < K) {
            asm volatile("s_waitcnt vmcnt(4)" ::: "memory");
        } else {
            asm volatile("s_waitcnt vmcnt(0)" ::: "memory");
        }
        asm volatile("s_barrier" ::: "memory");

        const int nk = k0 + 64;
        if (nk < K) {      // prefetch tile k+2 into buf (cur+2)%3
            int nb = cur + 2; if (nb >= 3) nb -= 3;
            async_copy16(gA0 + nk, lA[nb]);
            async_copy16(gA1 + nk, lA[nb] + 16 * 32);
            async_copy16(gB0 + nk, lB[nb]);
            async_copy16(gB1 + nk, lB[nb] + 16 * 32);
        }

        short8 af[4], bfr[4];
#pragma unroll
        for (int i = 0; i < 4; i++) {
            af[i]  = *(const short8*)(&As[cur][(wm + i * 16 + l16) * 32 + (quad ^ xorsw) * 8]);
            bfr[i] = *(const short8*)(&Bs[cur][(wn + i * 16 + l16) * 32 + (quad ^ xorsw) * 8]);
        }
#pragma unroll
        for (int mi = 0; mi < 4; mi++)
#pragma unroll
            for (int nj = 0; nj < 4; nj++)
                acc[mi][nj] = __builtin_amdgcn_mfma_f32_16x16x32_bf16(
                    af[mi], bfr[nj], acc[mi][nj], 0, 0, 0);
        cur += 1; if (cur >= 3) cur -= 3;
    }

    // epilogue: lane holds D[row=quad*4+i][col=l16] per 16x16 tile
    const int crow0 = m0 + wm + quad * 4;
    const int ccol0 = n0 + wn + l16;
    if (MODE == 3) {
        float* Cf = (float*)Cout_v;
#pragma unroll
        for (int mi = 0; mi < 4; mi++)
#pragma unroll
            for (int i = 0; i < 4; i++) {
                int rr = crow0 + mi * 16 + i;
#pragma unroll
                for (int nj = 0; nj < 4; nj++)
                    Cf[(size_t)rr * N + ccol0 + nj * 16] = acc[mi][nj][i];
            }
    } else if (MODE == 1) {
        unsigned short* Cb = (unsigned short*)Cout_v;
        float bv[4];
#pragma unroll
        for (int nj = 0; nj < 4; nj++) bv[nj] = bias[ccol0 + nj * 16];
#pragma unroll
        for (int mi = 0; mi < 4; mi++)
#pragma unroll
            for (int i = 0; i < 4; i++) {
                int rr = crow0 + mi * 16 + i;
#pragma unroll
                for (int nj = 0; nj < 4; nj++) {
                    float v = fmaxf(acc[mi][nj][i] + bv[nj], 0.f);
                    Cb[(size_t)rr * N + ccol0 + nj * 16] = f2bf(v);
                }
            }
    } else {  // MODE 2
        float* Cf = (float*)Cout_v;
        float bv[4];
#pragma unroll
        for (int nj = 0; nj < 4; nj++) bv[nj] = bias[ccol0 + nj * 16];
#pragma unroll
        for (int mi = 0; mi < 4; mi++)
#pragma unroll
            for (int i = 0; i < 4; i++) {
                int rr = crow0 + mi * 16 + i;
#pragma unroll
                for (int nj = 0; nj < 4; nj++) {
                    float v = acc[mi][nj][i] + bv[nj]
                            + bf2f(resid[(size_t)rr * N + ccol0 + nj * 16]);
                    Cf[(size_t)rr * N + ccol0 + nj * 16] = v;
                }
            }
    }
}

// ---------------------------------------------------------------------------
// softmax over the K=15 taps. wscore: TB x 256 fp32 (cols 0..239 valid, col
// index j = h*15+k). wconv out: TB x 240 fp32. One thread per (row, h).
// ---------------------------------------------------------------------------
__global__ void softmax_k(const float* __restrict__ wscore,
                          const float* __restrict__ b_lin,
                          float* __restrict__ wconv) {
    int gid = blockIdx.x * 256 + threadIdx.x;   // 0 .. TB*16-1
    int row = gid >> 4, hh = gid & 15;
    const float* p = wscore + (size_t)row * 256 + hh * 15;
    float v[K_TAP], mx = -1e30f;
#pragma unroll
    for (int k = 0; k < K_TAP; k++) {
        v[k] = p[k] + b_lin[hh * K_TAP + k];
        mx = fmaxf(mx, v[k]);
    }
    float s = 0.f;
#pragma unroll
    for (int k = 0; k < K_TAP; k++) { v[k] = __expf(v[k] - mx); s += v[k]; }
    float inv = 1.0f / s;
    float* q = wconv + (size_t)row * 240 + hh * K_TAP;
#pragma unroll
    for (int k = 0; k < K_TAP; k++) q[k] = v[k] * inv;
}

// ---------------------------------------------------------------------------
// conv_ln: causal dynamic conv + LayerNorm. One block per (t,b) row, 256 thr,
// each thread owns 4 consecutive channels. x is bf16 (pre-converted), y bf16.
// ---------------------------------------------------------------------------
__global__ __launch_bounds__(256)
void conv_ln(const unsigned short* __restrict__ x,
             const float* __restrict__ wconv,
             const float* __restrict__ ln_g,
             const float* __restrict__ ln_b,
             unsigned short* __restrict__ y) {
    __shared__ __align__(8) unsigned short xs[K_TAP][C_DIM];
    __shared__ float rbuf[8];
    const int r = blockIdx.x;       // t*B + b
    const int t = r >> 3;           // B_DIM == 8
    const int tid = threadIdx.x;
    const int c = tid * 4;

#pragma unroll
    for (int k = 0; k < K_TAP; k++) {
        uint2 val = make_uint2(0u, 0u);
        if (t + k >= K_TAP - 1)
            val = *(const uint2*)(x + ((size_t)r + (size_t)(k - (K_TAP - 1)) * B_DIM) * C_DIM + c);
        *(uint2*)(&xs[k][c]) = val;
    }
    __syncthreads();

    const float* wp = wconv + (size_t)r * 240 + (c >> 6) * K_TAP;
    float o0 = 0.f, o1 = 0.f, o2 = 0.f, o3 = 0.f;
#pragma unroll
    for (int k = 0; k < K_TAP; k++) {
        float w = wp[k];
        uint2 xv = *(const uint2*)(&xs[k][c]);
        o0 += w * bf2f((unsigned short)(xv.x & 0xffff));
        o1 += w * bf2f((unsigned short)(xv.x >> 16));
        o2 += w * bf2f((unsigned short)(xv.y & 0xffff));
        o3 += w * bf2f((unsigned short)(xv.y >> 16));
    }
    float s = o0 + o1 + o2 + o3;
    float s2 = o0 * o0 + o1 * o1 + o2 * o2 + o3 * o3;
#pragma unroll
    for (int off = 32; off > 0; off >>= 1) {
        s  += __shfl_down(s, off, 64);
        s2 += __shfl_down(s2, off, 64);
    }
    if ((tid & 63) == 0) { rbuf[tid >> 6] = s; rbuf[(tid >> 6) + 4] = s2; }
    __syncthreads();
    if (tid == 0) {
        rbuf[0] = rbuf[0] + rbuf[1] + rbuf[2] + rbuf[3];
        rbuf[4] = rbuf[4] + rbuf[5] + rbuf[6] + rbuf[7];
    }
    __syncthreads();
    float mu = rbuf[0] * (1.0f / C_DIM);
    float var = rbuf[4] * (1.0f / C_DIM) - mu * mu;
    float rs = rsqrtf(var + 1e-5f);

    float oo[4] = {o0, o1, o2, o3};
    unsigned short o16[4];
#pragma unroll
    for (int j = 0; j < 4; j++)
        o16[j] = f2bf((oo[j] - mu) * rs * ln_g[c + j] + ln_b[c + j]);
    uint2 outv;
    outv.x = (unsigned int)o16[0] | ((unsigned int)o16[1] << 16);
    outv.y = (unsigned int)o16[2] | ((unsigned int)o16[3] << 16);
    *(uint2*)(y + (size_t)r * C_DIM + c) = outv;
}

// ---------------------------------------------------------------------------
extern "C" void kernel_launch(void* const* d_in, const int* in_sizes, int n_in,
                              void* d_out, int out_size, void* d_ws, size_t ws_size,
                              hipStream_t stream) {
    const float* x     = (const float*)d_in[0];
    const float* w_lin = (const float*)d_in[1];
    const float* b_lin = (const float*)d_in[2];
    const float* ln_g  = (const float*)d_in[3];
    const float* ln_b  = (const float*)d_in[4];
    const float* fc1_w = (const float*)d_in[5];
    const float* fc1_b = (const float*)d_in[6];
    const float* fc2_w = (const float*)d_in[7];
    const float* fc2_b = (const float*)d_in[8];
    float* out = (float*)d_out;

    // workspace layout (bytes); total 112.5 MiB
    char* ws = (char*)d_ws;
    unsigned short* xb    = (unsigned short*)(ws);                      // TB x C   16 MiB
    unsigned short* fc1T  = (unsigned short*)(ws + 16777216);           // F x C     8 MiB
    unsigned short* fc2T  = (unsigned short*)(ws + 25165824);           // C x F     8 MiB
    unsigned short* wlinT = (unsigned short*)(ws + 33554432);           // 256 x C   0.5 MiB
    unsigned short* y     = (unsigned short*)(ws + 34078720);           // TB x C   16 MiB
    unsigned short* h     = (unsigned short*)(ws + 50855936);           // TB x F   64 MiB
    // wscore/wconv overlap h's region (both dead before h is written)
    float* wscore = (float*)(ws + 50855936);                            // TB x 256 fp32 (8 MiB)
    float* wconv  = (float*)(ws + 59244544);                            // TB x 240 fp32 (7.5 MiB)

    // x fp32 -> bf16
    cvt_bf16<<<TB * C_DIM / 1024, 256, 0, stream>>>(x, xb);

    dim3 tb(32, 8);
    // fc1_w: (C x F) -> fc1T (F x C)
    transpose_pad<<<dim3(F_DIM / 32, C_DIM / 32), tb, 0, stream>>>(fc1_w, fc1T, C_DIM, F_DIM, F_DIM);
    // fc2_w: (F x C) -> fc2T (C x F)
    transpose_pad<<<dim3(C_DIM / 32, F_DIM / 32), tb, 0, stream>>>(fc2_w, fc2T, F_DIM, C_DIM, C_DIM);
    // w_lin: (C x 240) -> wlinT (256 x C), rows 240..255 zero
    transpose_pad<<<dim3(256 / 32, C_DIM / 32), tb, 0, stream>>>(w_lin, wlinT, C_DIM, 240, 256);

    // conv-weight logits: wscore = xb @ w_lin  (TB x 256, fp32 out)
    gemm_bt<3><<<dim3(256 / 128, TB / 128), 256, 0, stream>>>(
        xb, wlinT, (void*)wscore, TB, 256, C_DIM, nullptr, nullptr);

    // softmax over taps
    softmax_k<<<TB * H_DIM / 256, 256, 0, stream>>>(wscore, b_lin, wconv);

    // dynamic conv + LayerNorm -> y (bf16)
    conv_ln<<<TB, 256, 0, stream>>>(xb, wconv, ln_g, ln_b, y);

    // h = relu(y @ fc1_w + fc1_b)  (bf16)
    gemm_bt<1><<<dim3(F_DIM / 128, TB / 128), 256, 0, stream>>>(
        y, fc1T, (void*)h, TB, F_DIM, C_DIM, fc1_b, nullptr);

    // out = h @ fc2_w + fc2_b + y  (fp32)
    gemm_bt<2><<<dim3(C_DIM / 128, TB / 128), 256, 0, stream>>>(
        h, fc2T, (void*)out, TB, C_DIM, F_DIM, fc2_b, y);
}

// Round 6
// 356.621 us; speedup vs baseline: 1.0677x; 1.0677x over previous
//
#include <hip/hip_runtime.h>

// ConvRecLayer: dynamic conv (H=16, K=15, causal) + LayerNorm + FFN(relu) + residual
// T=1024 B=8 C=1024 F=4096. Inputs/outputs fp32 (per reference); internal compute bf16 MFMA.

#define T_DIM 1024
#define B_DIM 8
#define C_DIM 1024
#define F_DIM 4096
#define H_DIM 16
#define K_TAP 15
#define TB (T_DIM * B_DIM)   // 8192 rows

typedef __attribute__((ext_vector_type(8))) short short8;
typedef __attribute__((ext_vector_type(4))) float f32x4;

__device__ __forceinline__ float bf2f(unsigned short u) {
    union { unsigned int i; float f; } v; v.i = ((unsigned int)u) << 16; return v.f;
}
__device__ __forceinline__ unsigned short f2bf(float f) {
    union { float f; unsigned int i; } v; v.f = f;
    unsigned int r = v.i + 0x7fffu + ((v.i >> 16) & 1u);  // RNE
    return (unsigned short)(r >> 16);
}

// async global->LDS DMA, 16B per lane: lane i reads gptr(lane) -> ldsbase + i*16
__device__ __forceinline__ void async_copy16(const void* gptr, void* lptr) {
    __builtin_amdgcn_global_load_lds(
        (const __attribute__((address_space(1))) void*)gptr,
        (__attribute__((address_space(3))) void*)lptr, 16, 0, 0);
}

// ---------------------------------------------------------------------------
// cvt_bf16: fp32 -> bf16, 4 elems/thread. n must be multiple of 1024.
// ---------------------------------------------------------------------------
__global__ void cvt_bf16(const float* __restrict__ in, unsigned short* __restrict__ out) {
    int i = (blockIdx.x * 256 + threadIdx.x) * 4;
    float4 v = *(const float4*)(in + i);
    unsigned short a = f2bf(v.x), b = f2bf(v.y), c = f2bf(v.z), d = f2bf(v.w);
    uint2 o;
    o.x = (unsigned int)a | ((unsigned int)b << 16);
    o.y = (unsigned int)c | ((unsigned int)d << 16);
    *(uint2*)(out + i) = o;
}

// ---------------------------------------------------------------------------
// transpose_pad: in is R x Cin (fp32, row-major). out is Cpad x R (bf16), rows
// >= Cin zero-filled. Grid: (Cpad/32, R/32), block (32,8).
// ---------------------------------------------------------------------------
__global__ void transpose_pad(const float* __restrict__ in,
                              unsigned short* __restrict__ out,
                              int R, int Cin, int Cpad) {
    __shared__ unsigned short tile[32][33];
    const int c0 = blockIdx.x * 32, r0 = blockIdx.y * 32;
    const int x = threadIdx.x, y = threadIdx.y;
#pragma unroll
    for (int j = 0; j < 4; j++) {
        int r = r0 + y + j * 8, c = c0 + x;
        unsigned short v = 0;
        if (c < Cin) v = f2bf(in[(size_t)r * Cin + c]);
        tile[y + j * 8][x] = v;
    }
    __syncthreads();
#pragma unroll
    for (int j = 0; j < 4; j++) {
        out[(size_t)(c0 + y + j * 8) * R + (r0 + x)] = tile[x][y + j * 8];
    }
}

// ---------------------------------------------------------------------------
// gemm_bt: C[M x N] = A[M x K] @ Bt[N x K]^T  (bf16 in, fp32 acc)
// 128x128 block tile, 4 waves each computing 64x64 via 4x4 MFMA 16x16x32 tiles.
// Round-4 proven structure: global_load_lds width=16 into DOUBLE-BUFFERED LDS,
// ONE __syncthreads per K-iteration (drains the tile-k DMA issued a full
// compute-phase earlier). Depth-2 vmcnt pipelining was tried (round 5) and
// REGRESSED — compiler-inserted vmcnt(0) before ds_reads collapses it.
// LDS layout [128 rows][32 k], XOR-swizzled on the GLOBAL address side
// (chunk kc of row r at slot kc ^ ((r>>1)&3)); fragment ds_read_b128s are
// verified conflict-free (SQ_LDS_BANK_CONFLICT = 0).
// Split-K via gridDim.z: each z computes a kz-long K-slice; MODE 3 writes its
// partial to Cout + z*M*N. For MODE 1/2 launch with gridDim.z=1, kz=K.
// MODE 1: bf16 out = relu(acc + bias[n])
// MODE 2: fp32 out = acc + bias[n] + resid[m][n]   (resid bf16)
// MODE 3: fp32 out = acc (partial per z)
// Requires M%128==0, N%128==0, kz%32==0, kz >= 64.
// ---------------------------------------------------------------------------
template <int MODE>
__global__ __launch_bounds__(256)
void gemm_bt(const unsigned short* __restrict__ A,
             const unsigned short* __restrict__ Bt,
             void* __restrict__ Cout_v,
             int M, int N, int K, int kz,
             const float* __restrict__ bias,
             const unsigned short* __restrict__ resid) {
    __shared__ __align__(16) unsigned short As[2][128 * 32];
    __shared__ __align__(16) unsigned short Bs[2][128 * 32];

    const int tid = threadIdx.x;
    const int m0 = blockIdx.y * 128;
    const int n0 = blockIdx.x * 128;
    const int kbase = blockIdx.z * kz;
    const int wave = tid >> 6, lane = tid & 63;
    const int quad = lane >> 4, l16 = lane & 15;
    const int wm = (wave >> 1) * 64;  // wave row offset in tile
    const int wn = (wave & 1) * 64;   // wave col offset in tile

    f32x4 acc[4][4];
#pragma unroll
    for (int i = 0; i < 4; i++)
#pragma unroll
        for (int j = 0; j < 4; j++) acc[i][j] = (f32x4){0.f, 0.f, 0.f, 0.f};

    // ---- DMA staging addresses -------------------------------------------
    // wave w stages rows [w*32, w*32+32) of both A and B tiles, as two
    // 16-row issues per operand. Lane i covers (row = i>>2, stored chunk
    // kc_s = i&3); the global chunk it fetches is kc_s ^ ((row>>1)&3).
    const int r_local = lane >> 2;                       // 0..15
    const int kc_g = (lane & 3) ^ ((lane >> 3) & 3);     // swizzled global chunk
    const unsigned short* gA0 = A + (size_t)(m0 + wave * 32 + r_local) * K + kbase + kc_g * 8;
    const unsigned short* gA1 = gA0 + (size_t)16 * K;
    const unsigned short* gB0 = Bt + (size_t)(n0 + wave * 32 + r_local) * K + kbase + kc_g * 8;
    const unsigned short* gB1 = gB0 + (size_t)16 * K;
    unsigned short* lA[2] = {&As[0][wave * 32 * 32], &As[1][wave * 32 * 32]};
    unsigned short* lB[2] = {&Bs[0][wave * 32 * 32], &Bs[1][wave * 32 * 32]};

    const int xorsw = (l16 >> 1) & 3;                    // fragment-read swizzle

    // prologue: stage tile 0 into buffer 0
    async_copy16(gA0, lA[0]);
    async_copy16(gA1, lA[0] + 16 * 32);
    async_copy16(gB0, lB[0]);
    async_copy16(gB1, lB[0] + 16 * 32);

    int buf = 0;
    for (int k0 = 0; k0 < kz; k0 += 32) {
        __syncthreads();   // drains own-wave DMA (tile k) + all waves' reads of buf^1

        const int nk = k0 + 32;
        if (nk < kz) {     // prefetch tile k+1 into the other buffer
            const int nb = buf ^ 1;
            async_copy16(gA0 + nk, lA[nb]);
            async_copy16(gA1 + nk, lA[nb] + 16 * 32);
            async_copy16(gB0 + nk, lB[nb]);
            async_copy16(gB1 + nk, lB[nb] + 16 * 32);
        }

        short8 af[4], bfr[4];
#pragma unroll
        for (int i = 0; i < 4; i++) {
            af[i]  = *(const short8*)(&As[buf][(wm + i * 16 + l16) * 32 + (quad ^ xorsw) * 8]);
            bfr[i] = *(const short8*)(&Bs[buf][(wn + i * 16 + l16) * 32 + (quad ^ xorsw) * 8]);
        }
#pragma unroll
        for (int mi = 0; mi < 4; mi++)
#pragma unroll
            for (int nj = 0; nj < 4; nj++)
                acc[mi][nj] = __builtin_amdgcn_mfma_f32_16x16x32_bf16(
                    af[mi], bfr[nj], acc[mi][nj], 0, 0, 0);
        buf ^= 1;
    }

    // epilogue: lane holds D[row=quad*4+i][col=l16] per 16x16 tile
    const int crow0 = m0 + wm + quad * 4;
    const int ccol0 = n0 + wn + l16;
    if (MODE == 3) {
        float* Cf = (float*)Cout_v + (size_t)blockIdx.z * M * N;
#pragma unroll
        for (int mi = 0; mi < 4; mi++)
#pragma unroll
            for (int i = 0; i < 4; i++) {
                int rr = crow0 + mi * 16 + i;
#pragma unroll
                for (int nj = 0; nj < 4; nj++)
                    Cf[(size_t)rr * N + ccol0 + nj * 16] = acc[mi][nj][i];
            }
    } else if (MODE == 1) {
        unsigned short* Cb = (unsigned short*)Cout_v;
        float bv[4];
#pragma unroll
        for (int nj = 0; nj < 4; nj++) bv[nj] = bias[ccol0 + nj * 16];
#pragma unroll
        for (int mi = 0; mi < 4; mi++)
#pragma unroll
            for (int i = 0; i < 4; i++) {
                int rr = crow0 + mi * 16 + i;
#pragma unroll
                for (int nj = 0; nj < 4; nj++) {
                    float v = fmaxf(acc[mi][nj][i] + bv[nj], 0.f);
                    Cb[(size_t)rr * N + ccol0 + nj * 16] = f2bf(v);
                }
            }
    } else {  // MODE 2
        float* Cf = (float*)Cout_v;
        float bv[4];
#pragma unroll
        for (int nj = 0; nj < 4; nj++) bv[nj] = bias[ccol0 + nj * 16];
#pragma unroll
        for (int mi = 0; mi < 4; mi++)
#pragma unroll
            for (int i = 0; i < 4; i++) {
                int rr = crow0 + mi * 16 + i;
#pragma unroll
                for (int nj = 0; nj < 4; nj++) {
                    float v = acc[mi][nj][i] + bv[nj]
                            + bf2f(resid[(size_t)rr * N + ccol0 + nj * 16]);
                    Cf[(size_t)rr * N + ccol0 + nj * 16] = v;
                }
            }
    }
}

// ---------------------------------------------------------------------------
// softmax over the K=15 taps, summing 4 split-K partials of wscore.
// wscore: 4 x [TB x 256] fp32 partials (cols 0..239 valid, col j = h*15+k).
// wconv out: TB x 240 fp32. One thread per (row, h).
// ---------------------------------------------------------------------------
#define WS_STRIDE ((size_t)TB * 256)
__global__ void softmax_k(const float* __restrict__ wscore,
                          const float* __restrict__ b_lin,
                          float* __restrict__ wconv) {
    int gid = blockIdx.x * 256 + threadIdx.x;   // 0 .. TB*16-1
    int row = gid >> 4, hh = gid & 15;
    const float* p = wscore + (size_t)row * 256 + hh * 15;
    float v[K_TAP], mx = -1e30f;
#pragma unroll
    for (int k = 0; k < K_TAP; k++) {
        v[k] = p[k] + p[k + WS_STRIDE] + p[k + 2 * WS_STRIDE] + p[k + 3 * WS_STRIDE]
             + b_lin[hh * K_TAP + k];
        mx = fmaxf(mx, v[k]);
    }
    float s = 0.f;
#pragma unroll
    for (int k = 0; k < K_TAP; k++) { v[k] = __expf(v[k] - mx); s += v[k]; }
    float inv = 1.0f / s;
    float* q = wconv + (size_t)row * 240 + hh * K_TAP;
#pragma unroll
    for (int k = 0; k < K_TAP; k++) q[k] = v[k] * inv;
}

// ---------------------------------------------------------------------------
// conv_ln8: causal dynamic conv + LayerNorm, 8 output rows per block.
// Block handles (b, t0..t0+7): stages the 22 shared x-rows (t0-14..t0+7) and
// the 8 wconv rows in LDS once (rows t..t+7 share 14/15 tap rows — 5x less
// global traffic than row-per-block). Each wave computes 2 full rows: lane
// owns 16 consecutive channels (h = lane>>2 is constant across them), LN
// mean/var via wave-local shuffle reduction (no barriers after staging).
// ---------------------------------------------------------------------------
__global__ __launch_bounds__(256)
void conv_ln8(const unsigned short* __restrict__ x,
              const float* __restrict__ wconv,
              const float* __restrict__ ln_g,
              const float* __restrict__ ln_b,
              unsigned short* __restrict__ y) {
    __shared__ __align__(16) unsigned short xs[22][C_DIM];  // 44 KiB
    __shared__ float wls[8 * 240];                          // 7.5 KiB
    const int blk = blockIdx.x;          // 0..1023
    const int b = blk & 7;
    const int t0 = (blk >> 3) * 8;
    const int tid = threadIdx.x;

    // stage 22 x-rows (t = t0-14 .. t0+7), 8B per thread per row
#pragma unroll
    for (int k = 0; k < 22; k++) {
        int t = t0 + k - 14;
        uint2 val = make_uint2(0u, 0u);
        if (t >= 0)
            val = *(const uint2*)(x + ((size_t)t * B_DIM + b) * C_DIM + tid * 4);
        *(uint2*)(&xs[k][tid * 4]) = val;
    }
    // stage 8 wconv rows
    for (int idx = tid; idx < 8 * 240; idx += 256) {
        int j = idx / 240, o = idx - j * 240;
        wls[idx] = wconv[((size_t)(t0 + j) * B_DIM + b) * 240 + o];
    }
    __syncthreads();

    const int wave = tid >> 6, lane = tid & 63;
    const int ch0 = lane * 16;
    const int h = lane >> 2;             // head index, constant over lane's 16 ch

    for (int rj = wave; rj < 8; rj += 4) {
        float acc[16];
#pragma unroll
        for (int i = 0; i < 16; i++) acc[i] = 0.f;
#pragma unroll
        for (int k = 0; k < K_TAP; k++) {
            float w = wls[rj * 240 + h * 15 + k];
            const unsigned short* xr = &xs[rj + k][ch0];
            uint4 p0 = *(const uint4*)(xr);
            uint4 p1 = *(const uint4*)(xr + 8);
            unsigned int uu[8] = {p0.x, p0.y, p0.z, p0.w, p1.x, p1.y, p1.z, p1.w};
#pragma unroll
            for (int q = 0; q < 8; q++) {
                acc[2 * q]     += w * bf2f((unsigned short)(uu[q] & 0xffff));
                acc[2 * q + 1] += w * bf2f((unsigned short)(uu[q] >> 16));
            }
        }
        float s = 0.f, s2 = 0.f;
#pragma unroll
        for (int i = 0; i < 16; i++) { s += acc[i]; s2 += acc[i] * acc[i]; }
#pragma unroll
        for (int off = 32; off > 0; off >>= 1) {
            s  += __shfl_xor(s, off, 64);
            s2 += __shfl_xor(s2, off, 64);
        }
        float mu = s * (1.0f / C_DIM);
        float var = s2 * (1.0f / C_DIM) - mu * mu;
        float rs = rsqrtf(var + 1e-5f);

        unsigned short o16[16];
#pragma unroll
        for (int i = 0; i < 16; i++)
            o16[i] = f2bf((acc[i] - mu) * rs * ln_g[ch0 + i] + ln_b[ch0 + i]);
        uint4 w0, w1;
        w0.x = (unsigned int)o16[0]  | ((unsigned int)o16[1]  << 16);
        w0.y = (unsigned int)o16[2]  | ((unsigned int)o16[3]  << 16);
        w0.z = (unsigned int)o16[4]  | ((unsigned int)o16[5]  << 16);
        w0.w = (unsigned int)o16[6]  | ((unsigned int)o16[7]  << 16);
        w1.x = (unsigned int)o16[8]  | ((unsigned int)o16[9]  << 16);
        w1.y = (unsigned int)o16[10] | ((unsigned int)o16[11] << 16);
        w1.z = (unsigned int)o16[12] | ((unsigned int)o16[13] << 16);
        w1.w = (unsigned int)o16[14] | ((unsigned int)o16[15] << 16);
        unsigned short* yr = y + ((size_t)(t0 + rj) * B_DIM + b) * C_DIM + ch0;
        *(uint4*)(yr) = w0;
        *(uint4*)(yr + 8) = w1;
    }
}

// ---------------------------------------------------------------------------
extern "C" void kernel_launch(void* const* d_in, const int* in_sizes, int n_in,
                              void* d_out, int out_size, void* d_ws, size_t ws_size,
                              hipStream_t stream) {
    const float* x     = (const float*)d_in[0];
    const float* w_lin = (const float*)d_in[1];
    const float* b_lin = (const float*)d_in[2];
    const float* ln_g  = (const float*)d_in[3];
    const float* ln_b  = (const float*)d_in[4];
    const float* fc1_w = (const float*)d_in[5];
    const float* fc1_b = (const float*)d_in[6];
    const float* fc2_w = (const float*)d_in[7];
    const float* fc2_b = (const float*)d_in[8];
    float* out = (float*)d_out;

    // workspace layout (bytes); total 112.5 MiB
    char* ws = (char*)d_ws;
    unsigned short* xb    = (unsigned short*)(ws);                      // TB x C   16 MiB
    unsigned short* fc1T  = (unsigned short*)(ws + 16777216);           // F x C     8 MiB
    unsigned short* fc2T  = (unsigned short*)(ws + 25165824);           // C x F     8 MiB
    unsigned short* wlinT = (unsigned short*)(ws + 33554432);           // 256 x C   0.5 MiB
    unsigned short* y     = (unsigned short*)(ws + 34078720);           // TB x C   16 MiB
    unsigned short* h     = (unsigned short*)(ws + 50855936);           // TB x F   64 MiB
    // wscore (4 split-K partials) + wconv overlap h's region (dead before fc1)
    float* wscore = (float*)(ws + 50855936);                            // 4 x TB x 256 fp32 (32 MiB)
    float* wconv  = (float*)(ws + 50855936 + 33554432);                 // TB x 240 fp32 (7.5 MiB)

    // x fp32 -> bf16
    cvt_bf16<<<TB * C_DIM / 1024, 256, 0, stream>>>(x, xb);

    dim3 tb(32, 8);
    // fc1_w: (C x F) -> fc1T (F x C)
    transpose_pad<<<dim3(F_DIM / 32, C_DIM / 32), tb, 0, stream>>>(fc1_w, fc1T, C_DIM, F_DIM, F_DIM);
    // fc2_w: (F x C) -> fc2T (C x F)
    transpose_pad<<<dim3(C_DIM / 32, F_DIM / 32), tb, 0, stream>>>(fc2_w, fc2T, F_DIM, C_DIM, C_DIM);
    // w_lin: (C x 240) -> wlinT (256 x C), rows 240..255 zero
    transpose_pad<<<dim3(256 / 32, C_DIM / 32), tb, 0, stream>>>(w_lin, wlinT, C_DIM, 240, 256);

    // conv-weight logits: wscore[z] = xb[:, z*256:(z+1)*256] @ w_lin-slice (split-K=4)
    gemm_bt<3><<<dim3(256 / 128, TB / 128, 4), 256, 0, stream>>>(
        xb, wlinT, (void*)wscore, TB, 256, C_DIM, C_DIM / 4, nullptr, nullptr);

    // softmax over taps (sums 4 partials)
    softmax_k<<<TB * H_DIM / 256, 256, 0, stream>>>(wscore, b_lin, wconv);

    // dynamic conv + LayerNorm -> y (bf16), 8 rows per block
    conv_ln8<<<TB / 8, 256, 0, stream>>>(xb, wconv, ln_g, ln_b, y);

    // h = relu(y @ fc1_w + fc1_b)  (bf16)
    gemm_bt<1><<<dim3(F_DIM / 128, TB / 128, 1), 256, 0, stream>>>(
        y, fc1T, (void*)h, TB, F_DIM, C_DIM, C_DIM, fc1_b, nullptr);

    // out = h @ fc2_w + fc2_b + y  (fp32)
    gemm_bt<2><<<dim3(C_DIM / 128, TB / 128, 1), 256, 0, stream>>>(
        h, fc2T, (void*)out, TB, C_DIM, F_DIM, F_DIM, fc2_b, y);
}

// Round 7
// 316.018 us; speedup vs baseline: 1.2049x; 1.1285x over previous
//
#include <hip/hip_runtime.h>

// ConvRecLayer: dynamic conv (H=16, K=15, causal) + LayerNorm + FFN(relu) + residual
// T=1024 B=8 C=1024 F=4096. Inputs/outputs fp32 (per reference); internal compute bf16 MFMA.

#define T_DIM 1024
#define B_DIM 8
#define C_DIM 1024
#define F_DIM 4096
#define H_DIM 16
#define K_TAP 15
#define TB (T_DIM * B_DIM)   // 8192 rows

typedef __attribute__((ext_vector_type(8))) short short8;
typedef __attribute__((ext_vector_type(4))) float f32x4;

__device__ __forceinline__ float bf2f(unsigned short u) {
    union { unsigned int i; float f; } v; v.i = ((unsigned int)u) << 16; return v.f;
}
__device__ __forceinline__ unsigned short f2bf(float f) {
    union { float f; unsigned int i; } v; v.f = f;
    unsigned int r = v.i + 0x7fffu + ((v.i >> 16) & 1u);  // RNE
    return (unsigned short)(r >> 16);
}

// async global->LDS DMA, 16B per lane: lane i reads gptr(lane) -> ldsbase + i*16
__device__ __forceinline__ void async_copy16(const void* gptr, void* lptr) {
    __builtin_amdgcn_global_load_lds(
        (const __attribute__((address_space(1))) void*)gptr,
        (__attribute__((address_space(3))) void*)lptr, 16, 0, 0);
}

// ---------------------------------------------------------------------------
// prep: fused fp32->bf16 convert of x + three fp32->bf16 transposes.
// Grid partition (256 threads each):
//   [0, 8192)          cvt x -> xb (4 elems/thread)
//   [8192, 12288)      fc1_w (C x F) -> fc1T (F x C)
//   [12288, 16384)     fc2_w (F x C) -> fc2T (C x F)
//   [16384, 16640)     w_lin (C x 240) -> wlinT (256 x C), rows 240..255 zero
// ---------------------------------------------------------------------------
__global__ __launch_bounds__(256)
void prep(const float* __restrict__ x, unsigned short* __restrict__ xb,
          const float* __restrict__ fc1_w, unsigned short* __restrict__ fc1T,
          const float* __restrict__ fc2_w, unsigned short* __restrict__ fc2T,
          const float* __restrict__ w_lin, unsigned short* __restrict__ wlinT) {
    const int bid = blockIdx.x;
    const int tid = threadIdx.x;
    if (bid < 8192) {
        int i = (bid * 256 + tid) * 4;
        float4 v = *(const float4*)(x + i);
        uint2 o;
        o.x = (unsigned int)f2bf(v.x) | ((unsigned int)f2bf(v.y) << 16);
        o.y = (unsigned int)f2bf(v.z) | ((unsigned int)f2bf(v.w) << 16);
        *(uint2*)(xb + i) = o;
        return;
    }
    // transpose path
    const float* in; unsigned short* out; int R, Cin, c0, r0;
    if (bid < 12288) {
        int idx = bid - 8192;                 // grid (128, 32)
        in = fc1_w; out = fc1T; R = C_DIM; Cin = F_DIM;
        c0 = (idx & 127) * 32; r0 = (idx >> 7) * 32;
    } else if (bid < 16384) {
        int idx = bid - 12288;                // grid (32, 128)
        in = fc2_w; out = fc2T; R = F_DIM; Cin = C_DIM;
        c0 = (idx & 31) * 32; r0 = (idx >> 5) * 32;
    } else {
        int idx = bid - 16384;                // grid (8, 32)
        in = w_lin; out = wlinT; R = C_DIM; Cin = 240;
        c0 = (idx & 7) * 32; r0 = (idx >> 3) * 32;
    }
    __shared__ unsigned short tile[32][33];
    const int xx = tid & 31, yy = tid >> 5;   // 32 x 8
#pragma unroll
    for (int j = 0; j < 4; j++) {
        int r = r0 + yy + j * 8, c = c0 + xx;
        unsigned short v = 0;
        if (c < Cin) v = f2bf(in[(size_t)r * Cin + c]);
        tile[yy + j * 8][xx] = v;
    }
    __syncthreads();
#pragma unroll
    for (int j = 0; j < 4; j++) {
        out[(size_t)(c0 + yy + j * 8) * R + (r0 + xx)] = tile[xx][yy + j * 8];
    }
}

// ---------------------------------------------------------------------------
// gemm_bt: C[M x N] = A[M x K] @ Bt[N x K]^T  (bf16 in, fp32 acc)
// 128x128 block tile, 4 waves each computing 64x64 via 4x4 MFMA 16x16x32 tiles.
// BK=64 K-loop: 32 MFMA per barrier (2x the round-4 amortization), DMA-staged
// via global_load_lds width=16 into DOUBLE-BUFFERED LDS (64 KiB total, still
// 2 blocks/CU), ONE __syncthreads per iteration (round-4 proven; explicit
// vmcnt pipelining regressed in round 5).
// LDS tile [128 rows][64 k]: 16B chunk c of row r stored at slot c ^ (r&7)
// (swizzle applied on the GLOBAL address side; DMA LDS dest is hard-wired
// lane-contiguous). Fragment ds_read_b128: per quad, slots = c ^ (l16&7) hit
// each bank-group with exactly 2 lanes -> conflict-free (2-way is free, m136).
// SWAP=1 puts the m-tile on blockIdx.x so the 8 n-tile blocks sharing an
// A(m)-tile get linear ids == same mod 8 -> same XCD -> L2-served reuse (fc2).
// Split-K via gridDim.z (MODE 3 writes partial to Cout + z*M*N).
// MODE 1: bf16 out = relu(acc + bias[n])
// MODE 2: fp32 out = acc + bias[n] + resid[m][n]   (resid bf16)
// MODE 3: fp32 out = acc (partial per z)
// Requires M%128==0, N%128==0, kz%64==0, kz >= 128.
// ---------------------------------------------------------------------------
template <int MODE, int SWAP>
__global__ __launch_bounds__(256)
void gemm_bt(const unsigned short* __restrict__ A,
             const unsigned short* __restrict__ Bt,
             void* __restrict__ Cout_v,
             int M, int N, int K, int kz,
             const float* __restrict__ bias,
             const unsigned short* __restrict__ resid) {
    __shared__ __align__(16) unsigned short As[2][128 * 64];
    __shared__ __align__(16) unsigned short Bs[2][128 * 64];

    const int tid = threadIdx.x;
    const int m0 = (SWAP ? blockIdx.x : blockIdx.y) * 128;
    const int n0 = (SWAP ? blockIdx.y : blockIdx.x) * 128;
    const int kbase = blockIdx.z * kz;
    const int wave = tid >> 6, lane = tid & 63;
    const int quad = lane >> 4, l16 = lane & 15;
    const int wm = (wave >> 1) * 64;  // wave row offset in tile
    const int wn = (wave & 1) * 64;   // wave col offset in tile

    f32x4 acc[4][4];
#pragma unroll
    for (int i = 0; i < 4; i++)
#pragma unroll
        for (int j = 0; j < 4; j++) acc[i][j] = (f32x4){0.f, 0.f, 0.f, 0.f};

    // ---- DMA staging addresses -------------------------------------------
    // wave w stages rows [w*32, w*32+32) of A and B as 4 issues of 8 rows
    // each per operand. Lane i covers (row = i>>3, stored slot = i&7); the
    // global chunk it fetches is (i&7) ^ ((i>>3)&7).
    const int rsub = lane >> 3;                   // 0..7
    const int gch = (lane & 7) ^ rsub;            // swizzled global chunk
    const unsigned short* gA = A + (size_t)(m0 + wave * 32 + rsub) * K + kbase + gch * 8;
    const unsigned short* gB = Bt + (size_t)(n0 + wave * 32 + rsub) * K + kbase + gch * 8;
    unsigned short* lA[2] = {&As[0][wave * 32 * 64], &As[1][wave * 32 * 64]};
    unsigned short* lB[2] = {&Bs[0][wave * 32 * 64], &Bs[1][wave * 32 * 64]};

    // prologue: stage tile 0 into buffer 0
#pragma unroll
    for (int j = 0; j < 4; j++) {
        async_copy16(gA + (size_t)j * 8 * K, lA[0] + j * 8 * 64);
        async_copy16(gB + (size_t)j * 8 * K, lB[0] + j * 8 * 64);
    }

    const int swz = l16 & 7;                      // fragment-read swizzle
    int buf = 0;
    for (int k0 = 0; k0 < kz; k0 += 64) {
        __syncthreads();   // drains own-wave DMA (tile k) + all waves' reads of buf^1

        const int nk = k0 + 64;
        if (nk < kz) {     // prefetch tile k+1 into the other buffer
            const int nb = buf ^ 1;
#pragma unroll
            for (int j = 0; j < 4; j++) {
                async_copy16(gA + nk + (size_t)j * 8 * K, lA[nb] + j * 8 * 64);
                async_copy16(gB + nk + (size_t)j * 8 * K, lB[nb] + j * 8 * 64);
            }
        }

        short8 af[2][4], bfr[2][4];
#pragma unroll
        for (int kk = 0; kk < 2; kk++) {
            const int c = kk * 4 + quad;          // global chunk for this kk
#pragma unroll
            for (int i = 0; i < 4; i++) {
                af[kk][i]  = *(const short8*)(&As[buf][(wm + i * 16 + l16) * 64 + (c ^ swz) * 8]);
                bfr[kk][i] = *(const short8*)(&Bs[buf][(wn + i * 16 + l16) * 64 + (c ^ swz) * 8]);
            }
        }
#pragma unroll
        for (int kk = 0; kk < 2; kk++)
#pragma unroll
            for (int mi = 0; mi < 4; mi++)
#pragma unroll
                for (int nj = 0; nj < 4; nj++)
                    acc[mi][nj] = __builtin_amdgcn_mfma_f32_16x16x32_bf16(
                        af[kk][mi], bfr[kk][nj], acc[mi][nj], 0, 0, 0);
        buf ^= 1;
    }

    // epilogue: lane holds D[row=quad*4+i][col=l16] per 16x16 tile
    const int crow0 = m0 + wm + quad * 4;
    const int ccol0 = n0 + wn + l16;
    if (MODE == 3) {
        float* Cf = (float*)Cout_v + (size_t)blockIdx.z * M * N;
#pragma unroll
        for (int mi = 0; mi < 4; mi++)
#pragma unroll
            for (int i = 0; i < 4; i++) {
                int rr = crow0 + mi * 16 + i;
#pragma unroll
                for (int nj = 0; nj < 4; nj++)
                    Cf[(size_t)rr * N + ccol0 + nj * 16] = acc[mi][nj][i];
            }
    } else if (MODE == 1) {
        unsigned short* Cb = (unsigned short*)Cout_v;
        float bv[4];
#pragma unroll
        for (int nj = 0; nj < 4; nj++) bv[nj] = bias[ccol0 + nj * 16];
#pragma unroll
        for (int mi = 0; mi < 4; mi++)
#pragma unroll
            for (int i = 0; i < 4; i++) {
                int rr = crow0 + mi * 16 + i;
#pragma unroll
                for (int nj = 0; nj < 4; nj++) {
                    float v = fmaxf(acc[mi][nj][i] + bv[nj], 0.f);
                    Cb[(size_t)rr * N + ccol0 + nj * 16] = f2bf(v);
                }
            }
    } else {  // MODE 2
        float* Cf = (float*)Cout_v;
        float bv[4];
#pragma unroll
        for (int nj = 0; nj < 4; nj++) bv[nj] = bias[ccol0 + nj * 16];
#pragma unroll
        for (int mi = 0; mi < 4; mi++)
#pragma unroll
            for (int i = 0; i < 4; i++) {
                int rr = crow0 + mi * 16 + i;
#pragma unroll
                for (int nj = 0; nj < 4; nj++) {
                    float v = acc[mi][nj][i] + bv[nj]
                            + bf2f(resid[(size_t)rr * N + ccol0 + nj * 16]);
                    Cf[(size_t)rr * N + ccol0 + nj * 16] = v;
                }
            }
    }
}

// ---------------------------------------------------------------------------
// conv_ln8s: fused tap-softmax + causal dynamic conv + LayerNorm, 8 rows/blk.
// Block handles (b, t0..t0+7). Threads 0..127 first compute the 8x16 per-row
// per-head softmaxes directly from the 4 split-K wscore partials into LDS
// (kills the wconv global round-trip). Then stages the 22 shared x-rows and
// computes conv + LN as in round 6 (verified): each wave does 2 full rows,
// lane owns 16 consecutive channels, wave-local shuffle reduction.
// ---------------------------------------------------------------------------
#define WS_STRIDE ((size_t)TB * 256)
__global__ __launch_bounds__(256)
void conv_ln8s(const unsigned short* __restrict__ x,
               const float* __restrict__ wscore,
               const float* __restrict__ b_lin,
               const float* __restrict__ ln_g,
               const float* __restrict__ ln_b,
               unsigned short* __restrict__ y) {
    __shared__ __align__(16) unsigned short xs[22][C_DIM];  // 44 KiB
    __shared__ float wls[8 * 240];                          // 7.5 KiB
    const int blk = blockIdx.x;          // 0..1023
    const int b = blk & 7;
    const int t0 = (blk >> 3) * 8;
    const int tid = threadIdx.x;

    // in-block softmax: thread (rj, h) for tid < 128
    if (tid < 128) {
        const int rj = tid >> 4, hh = tid & 15;
        const size_t row = (size_t)(t0 + rj) * B_DIM + b;
        const float* p = wscore + row * 256 + hh * 15;
        float v[K_TAP], mx = -1e30f;
#pragma unroll
        for (int k = 0; k < K_TAP; k++) {
            v[k] = p[k] + p[k + WS_STRIDE] + p[k + 2 * WS_STRIDE] + p[k + 3 * WS_STRIDE]
                 + b_lin[hh * K_TAP + k];
            mx = fmaxf(mx, v[k]);
        }
        float s = 0.f;
#pragma unroll
        for (int k = 0; k < K_TAP; k++) { v[k] = __expf(v[k] - mx); s += v[k]; }
        float inv = 1.0f / s;
#pragma unroll
        for (int k = 0; k < K_TAP; k++) wls[rj * 240 + hh * K_TAP + k] = v[k] * inv;
    }

    // stage 22 x-rows (t = t0-14 .. t0+7), 8B per thread per row
#pragma unroll
    for (int k = 0; k < 22; k++) {
        int t = t0 + k - 14;
        uint2 val = make_uint2(0u, 0u);
        if (t >= 0)
            val = *(const uint2*)(x + ((size_t)t * B_DIM + b) * C_DIM + tid * 4);
        *(uint2*)(&xs[k][tid * 4]) = val;
    }
    __syncthreads();

    const int wave = tid >> 6, lane = tid & 63;
    const int ch0 = lane * 16;
    const int h = lane >> 2;             // head index, constant over lane's 16 ch

    for (int rj = wave; rj < 8; rj += 4) {
        float acc[16];
#pragma unroll
        for (int i = 0; i < 16; i++) acc[i] = 0.f;
#pragma unroll
        for (int k = 0; k < K_TAP; k++) {
            float w = wls[rj * 240 + h * 15 + k];
            const unsigned short* xr = &xs[rj + k][ch0];
            uint4 p0 = *(const uint4*)(xr);
            uint4 p1 = *(const uint4*)(xr + 8);
            unsigned int uu[8] = {p0.x, p0.y, p0.z, p0.w, p1.x, p1.y, p1.z, p1.w};
#pragma unroll
            for (int q = 0; q < 8; q++) {
                acc[2 * q]     += w * bf2f((unsigned short)(uu[q] & 0xffff));
                acc[2 * q + 1] += w * bf2f((unsigned short)(uu[q] >> 16));
            }
        }
        float s = 0.f, s2 = 0.f;
#pragma unroll
        for (int i = 0; i < 16; i++) { s += acc[i]; s2 += acc[i] * acc[i]; }
#pragma unroll
        for (int off = 32; off > 0; off >>= 1) {
            s  += __shfl_xor(s, off, 64);
            s2 += __shfl_xor(s2, off, 64);
        }
        float mu = s * (1.0f / C_DIM);
        float var = s2 * (1.0f / C_DIM) - mu * mu;
        float rs = rsqrtf(var + 1e-5f);

        unsigned short o16[16];
#pragma unroll
        for (int i = 0; i < 16; i++)
            o16[i] = f2bf((acc[i] - mu) * rs * ln_g[ch0 + i] + ln_b[ch0 + i]);
        uint4 w0, w1;
        w0.x = (unsigned int)o16[0]  | ((unsigned int)o16[1]  << 16);
        w0.y = (unsigned int)o16[2]  | ((unsigned int)o16[3]  << 16);
        w0.z = (unsigned int)o16[4]  | ((unsigned int)o16[5]  << 16);
        w0.w = (unsigned int)o16[6]  | ((unsigned int)o16[7]  << 16);
        w1.x = (unsigned int)o16[8]  | ((unsigned int)o16[9]  << 16);
        w1.y = (unsigned int)o16[10] | ((unsigned int)o16[11] << 16);
        w1.z = (unsigned int)o16[12] | ((unsigned int)o16[13] << 16);
        w1.w = (unsigned int)o16[14] | ((unsigned int)o16[15] << 16);
        unsigned short* yr = y + ((size_t)(t0 + rj) * B_DIM + b) * C_DIM + ch0;
        *(uint4*)(yr) = w0;
        *(uint4*)(yr + 8) = w1;
    }
}

// ---------------------------------------------------------------------------
extern "C" void kernel_launch(void* const* d_in, const int* in_sizes, int n_in,
                              void* d_out, int out_size, void* d_ws, size_t ws_size,
                              hipStream_t stream) {
    const float* x     = (const float*)d_in[0];
    const float* w_lin = (const float*)d_in[1];
    const float* b_lin = (const float*)d_in[2];
    const float* ln_g  = (const float*)d_in[3];
    const float* ln_b  = (const float*)d_in[4];
    const float* fc1_w = (const float*)d_in[5];
    const float* fc1_b = (const float*)d_in[6];
    const float* fc2_w = (const float*)d_in[7];
    const float* fc2_b = (const float*)d_in[8];
    float* out = (float*)d_out;

    // workspace layout (bytes); total 112.5 MiB
    char* ws = (char*)d_ws;
    unsigned short* xb    = (unsigned short*)(ws);                      // TB x C   16 MiB
    unsigned short* fc1T  = (unsigned short*)(ws + 16777216);           // F x C     8 MiB
    unsigned short* fc2T  = (unsigned short*)(ws + 25165824);           // C x F     8 MiB
    unsigned short* wlinT = (unsigned short*)(ws + 33554432);           // 256 x C   0.5 MiB
    unsigned short* y     = (unsigned short*)(ws + 34078720);           // TB x C   16 MiB
    unsigned short* h     = (unsigned short*)(ws + 50855936);           // TB x F   64 MiB
    // wscore (4 split-K partials) overlaps h's region (dead before fc1)
    float* wscore = (float*)(ws + 50855936);                            // 4 x TB x 256 fp32 (32 MiB)

    // fused convert + transposes (1 launch instead of 4)
    prep<<<16640, 256, 0, stream>>>(x, xb, fc1_w, fc1T, fc2_w, fc2T, w_lin, wlinT);

    // conv-weight logits: wscore[z] = xb[:, z*256:(z+1)*256] @ w_lin-slice (split-K=4)
    gemm_bt<3, 0><<<dim3(256 / 128, TB / 128, 4), 256, 0, stream>>>(
        xb, wlinT, (void*)wscore, TB, 256, C_DIM, C_DIM / 4, nullptr, nullptr);

    // fused softmax + dynamic conv + LayerNorm -> y (bf16), 8 rows per block
    conv_ln8s<<<TB / 8, 256, 0, stream>>>(xb, wscore, b_lin, ln_g, ln_b, y);

    // h = relu(y @ fc1_w + fc1_b)  (bf16)
    gemm_bt<1, 0><<<dim3(F_DIM / 128, TB / 128, 1), 256, 0, stream>>>(
        y, fc1T, (void*)h, TB, F_DIM, C_DIM, C_DIM, fc1_b, nullptr);

    // out = h @ fc2_w + fc2_b + y  (fp32); m-tile on x for same-XCD h reuse
    gemm_bt<2, 1><<<dim3(TB / 128, C_DIM / 128, 1), 256, 0, stream>>>(
        h, fc2T, (void*)out, TB, C_DIM, F_DIM, F_DIM, fc2_b, y);
}